// Round 9
// baseline (491.281 us; speedup 1.0000x reference)
//
#include <hip/hip_runtime.h>
#include <stdint.h>

// Triaffine: out[b,z,x,y] = sum_{i,j,k} xb[x,i] z[z,k] W[i,k,j] yb[y,j]
// B=4, S=128, D=512.  W: [513][512][513] f32 (i,k,j), elem (i,k,j) at (i*512+k)*513+j.
//
// Decomposition (bias split so all GEMM dims are 512):
//   M[bz,i,j] = sum_k z[bz,k] W[i,k,j]        (i,j < 512)   -- kernel G1, bf16 out
//   per bz:  R[i,y] = sum_j M[i,j] Ybf[y,j]                  -- kernel G2 pass-2
//            out[x,y] = sum_i Xbf[x,i] R[i,y] + u[x]+v[y]+d  -- kernel G2 pass-3
//   a[bz,i] = sum_k z W[i,k,512], c[bz,j] = sum_k z W[512,k,j], d = sum_k z W[512,k,512]

typedef __attribute__((ext_vector_type(8))) short bf16x8;
typedef __attribute__((ext_vector_type(4))) float f32x4;

__device__ __forceinline__ unsigned short f2bf(float f) {
    unsigned int u = __float_as_uint(f);
    u += 0x7fffu + ((u >> 16) & 1u);      // RNE
    return (unsigned short)(u >> 16);
}

__device__ __forceinline__ void gload_lds16(const void* g, void* l) {
    __builtin_amdgcn_global_load_lds((const __attribute__((address_space(1))) void*)g,
                                     (__attribute__((address_space(3))) void*)l, 16, 0, 0);
}

// ---------------- cast x,y,z -> bf16 ----------------
__global__ __launch_bounds__(256) void k_cast(const float* __restrict__ x,
    const float* __restrict__ y, const float* __restrict__ z,
    unsigned short* __restrict__ xbf, unsigned short* __restrict__ ybf,
    unsigned short* __restrict__ zbf)
{
    int t = blockIdx.x * 256 + threadIdx.x;   // 98304 threads, 8 elems each
    int arr = t >> 15;
    int off = (t & 32767) * 8;
    const float* src = (arr == 0) ? x : (arr == 1) ? y : z;
    unsigned short* dst = (arr == 0) ? xbf : (arr == 1) ? ybf : zbf;
    float4 a = *(const float4*)(src + off);
    float4 b = *(const float4*)(src + off + 4);
    uint4 o;
    o.x = f2bf(a.x) | ((unsigned)f2bf(a.y) << 16);
    o.y = f2bf(a.z) | ((unsigned)f2bf(a.w) << 16);
    o.z = f2bf(b.x) | ((unsigned)f2bf(b.y) << 16);
    o.w = f2bf(b.z) | ((unsigned)f2bf(b.w) << 16);
    *(uint4*)(dst + off) = o;
}

// ---------------- bias-edge GEMMs ----------------
__global__ __launch_bounds__(256) void k_edge(const float* __restrict__ z,
    const float* __restrict__ w, float* __restrict__ a_arr,
    float* __restrict__ c_arr, float* __restrict__ d_arr)
{
    __shared__ float Zs[64][33];
    __shared__ float Bs[32][65];
    int t = threadIdx.x;
    int mb = blockIdx.x % 17, bzb = blockIdx.x / 17;
    int tr = t >> 4, tc = t & 15;
    float acc[4][4] = {};
    for (int k0 = 0; k0 < 512; k0 += 32) {
        __syncthreads();
        {   int row = t >> 2, ko = (t & 3) * 8;
            const float* p = z + (bzb * 64 + row) * 512 + k0 + ko;
            float4 v0 = ((const float4*)p)[0], v1 = ((const float4*)p)[1];
            Zs[row][ko + 0] = v0.x; Zs[row][ko + 1] = v0.y; Zs[row][ko + 2] = v0.z; Zs[row][ko + 3] = v0.w;
            Zs[row][ko + 4] = v1.x; Zs[row][ko + 5] = v1.y; Zs[row][ko + 6] = v1.z; Zs[row][ko + 7] = v1.w;
        }
        {   int kr = t >> 3, mo = (t & 7) * 8;
            for (int e = 0; e < 8; ++e) {
                int m = mb * 64 + mo + e;
                float v = 0.f;
                int krow = k0 + kr;
                if (m < 512)        v = w[(m * 512 + krow) * 513 + 512];
                else if (m < 1024)  v = w[(262144 + krow) * 513 + (m - 512)];
                else if (m == 1024) v = w[(262144 + krow) * 513 + 512];
                Bs[kr][mo + e] = v;
            }
        }
        __syncthreads();
        for (int kk = 0; kk < 32; ++kk) {
            float zr[4], br[4];
            for (int r = 0; r < 4; ++r) zr[r] = Zs[tr * 4 + r][kk];
            for (int c = 0; c < 4; ++c) br[c] = Bs[kk][tc * 4 + c];
            for (int r = 0; r < 4; ++r)
                for (int c = 0; c < 4; ++c) acc[r][c] += zr[r] * br[c];
        }
    }
    for (int r = 0; r < 4; ++r)
        for (int c = 0; c < 4; ++c) {
            int bz = bzb * 64 + tr * 4 + r;
            int m = mb * 64 + tc * 4 + c;
            if (m < 512)        a_arr[bz * 512 + m] = acc[r][c];
            else if (m < 1024)  c_arr[bz * 512 + (m - 512)] = acc[r][c];
            else if (m == 1024) d_arr[bz] = acc[r][c];
        }
}

// ---------------- G1 v5: 8-phase-style schedule (T3+T4+T5) ----------------
// BM=512 (all bz; W streamed once), BN=128, BK=32, 16 K-steps, 2 phases/step.
// 8 waves = 4 bzg x 2 jg; wave tile 128bz x 64j; acc[8][4].
// Phase p = {ds_read p's frags | issue next staging -> s_barrier -> lgkmcnt(0)
//            -> setprio(1) 16 MFMA setprio(0) -> s_barrier}.
// Counted vmcnt ONCE per step: pack's auto-wait drains W(ks+1) only (FIFO:
// [W(ks+1)8, Z(ks+1)4, W(ks+2)8] -> vmcnt(12)); explicit vmcnt(8) drains
// Z(ks+1); W(ks+2) stays in flight across all barriers.
__global__ __launch_bounds__(512, 2) void k_gemm1(const unsigned short* __restrict__ zbf,
    const float* __restrict__ w, unsigned short* __restrict__ Mws)
{
    extern __shared__ unsigned char smem[];
    unsigned char* Zb0 = smem;                 // [512 rows][32 k] bf16 = 32 KB
    unsigned char* Zb1 = smem + 32768;
    unsigned char* Bb0 = smem + 65536;         // [128 j][32 k] bf16 = 8 KB
    unsigned char* Bb1 = smem + 73728;         // total 81920 B

    int nwg = gridDim.x, cpx = nwg >> 3;
    int bid = blockIdx.x;
    int swz = (bid & 7) * cpx + (bid >> 3);    // XCD swizzle (nwg % 8 == 0)
    int iloc = swz >> 2, jb = swz & 3;
    int j0 = jb * 128;
    int t = threadIdx.x, wid = t >> 6, lane = t & 63;
    int bzg = wid >> 1, jg = wid & 1;
    int l15 = lane & 15, l4 = lane >> 4;

    int arow = lane >> 2;
    int akc  = (lane & 3) ^ ((lane >> 3) & 3);
    const unsigned short* zbase = zbf + (size_t)(wid * 64 + arow) * 512 + akc * 8;

    int jB = t & 127, kq8 = t >> 7;
    const float* wb = w + (size_t)iloc * 262656 + (size_t)(kq8 * 8) * 513 + j0 + jB;
    int bwoff = jB * 64 + ((kq8 ^ ((jB >> 1) & 3)) * 16);

    int aoff = (bzg * 128 + l15) * 64 + ((l4 ^ ((l15 >> 1) & 3)) * 16);
    int boff = (jg * 64 + l15) * 64 + ((l4 ^ ((l15 >> 1) & 3)) * 16);

    f32x4 acc[8][4];
    #pragma unroll
    for (int mt = 0; mt < 8; ++mt)
        #pragma unroll
        for (int nt = 0; nt < 4; ++nt) acc[mt][nt] = (f32x4){0.f, 0.f, 0.f, 0.f};

    float wr[2][8];

    // ---- prologue: Z(0) glds, W(0)+W(1) loads, pack W(0) ----
    #pragma unroll
    for (int q = 0; q < 4; ++q)
        gload_lds16(zbase + q * 8192, Zb0 + wid * 4096 + q * 1024);
    {
        #pragma unroll
        for (int e = 0; e < 8; ++e) wr[0][e] = __builtin_nontemporal_load(wb + (size_t)e * 513);
        const float* wp = wb + (size_t)32 * 513;
        #pragma unroll
        for (int e = 0; e < 8; ++e) wr[1][e] = __builtin_nontemporal_load(wp + (size_t)e * 513);
        // pack W(0): auto-wait vmcnt(8) drains Z(0)+W(0), keeps W(1)
        uint4 pk;
        pk.x = f2bf(wr[0][0]) | ((unsigned)f2bf(wr[0][1]) << 16);
        pk.y = f2bf(wr[0][2]) | ((unsigned)f2bf(wr[0][3]) << 16);
        pk.z = f2bf(wr[0][4]) | ((unsigned)f2bf(wr[0][5]) << 16);
        pk.w = f2bf(wr[0][6]) | ((unsigned)f2bf(wr[0][7]) << 16);
        *(uint4*)(Bb0 + bwoff) = pk;
    }
    asm volatile("s_waitcnt lgkmcnt(0)" ::: "memory");
    __builtin_amdgcn_s_barrier();
    __builtin_amdgcn_sched_barrier(0);

    #pragma unroll
    for (int ks = 0; ks < 16; ++ks) {
        const int cur = ks & 1;
        unsigned char* Zcur  = cur ? Zb1 : Zb0;
        unsigned char* Znext = cur ? Zb0 : Zb1;
        unsigned char* Bcur  = cur ? Bb1 : Bb0;
        unsigned char* Bnext = cur ? Bb0 : Bb1;

        // ======== phase 0 ========
        // issue next-step staging (stays in flight under both MFMA clusters)
        if (ks < 15) {
            #pragma unroll
            for (int q = 0; q < 4; ++q)
                gload_lds16(zbase + (ks + 1) * 32 + q * 8192, Znext + wid * 4096 + q * 1024);
        }
        if (ks < 14) {
            const float* wp = wb + (size_t)(ks + 2) * 32 * 513;
            #pragma unroll
            for (int e = 0; e < 8; ++e) wr[cur][e] = __builtin_nontemporal_load(wp + (size_t)e * 513);
        }
        // this phase's fragments
        bf16x8 bfr[4];
        #pragma unroll
        for (int nt = 0; nt < 4; ++nt)
            bfr[nt] = *(const bf16x8*)(Bcur + boff + nt * 1024);
        bf16x8 afr0[4];
        #pragma unroll
        for (int mt = 0; mt < 4; ++mt)
            afr0[mt] = *(const bf16x8*)(Zcur + aoff + mt * 1024);
        __builtin_amdgcn_s_barrier();                       // bar 1
        asm volatile("s_waitcnt lgkmcnt(0)" ::: "memory");
        __builtin_amdgcn_sched_barrier(0);
        __builtin_amdgcn_s_setprio(1);
        #pragma unroll
        for (int mt = 0; mt < 4; ++mt)
            #pragma unroll
            for (int nt = 0; nt < 4; ++nt)
                acc[mt][nt] = __builtin_amdgcn_mfma_f32_16x16x32_bf16(afr0[mt], bfr[nt], acc[mt][nt], 0, 0, 0);
        __builtin_amdgcn_s_setprio(0);
        __builtin_amdgcn_s_barrier();                       // bar 2
        __builtin_amdgcn_sched_barrier(0);

        // ======== phase 1 ========
        bf16x8 afr1[4];
        #pragma unroll
        for (int mt = 0; mt < 4; ++mt)
            afr1[mt] = *(const bf16x8*)(Zcur + aoff + (mt + 4) * 1024);
        if (ks < 15) {
            // pack W(ks+1): auto-wait vmcnt(12) drains W(ks+1) only
            uint4 pk;
            pk.x = f2bf(wr[cur ^ 1][0]) | ((unsigned)f2bf(wr[cur ^ 1][1]) << 16);
            pk.y = f2bf(wr[cur ^ 1][2]) | ((unsigned)f2bf(wr[cur ^ 1][3]) << 16);
            pk.z = f2bf(wr[cur ^ 1][4]) | ((unsigned)f2bf(wr[cur ^ 1][5]) << 16);
            pk.w = f2bf(wr[cur ^ 1][6]) | ((unsigned)f2bf(wr[cur ^ 1][7]) << 16);
            *(uint4*)(Bnext + bwoff) = pk;
        }
        if (ks < 14) {
            asm volatile("s_waitcnt vmcnt(8) lgkmcnt(0)" ::: "memory");  // drain Z(ks+1), keep W(ks+2)
        } else if (ks == 14) {
            asm volatile("s_waitcnt vmcnt(0) lgkmcnt(0)" ::: "memory");
        } else {
            asm volatile("s_waitcnt lgkmcnt(0)" ::: "memory");
        }
        if (ks < 15) {
            __builtin_amdgcn_s_barrier();                   // bar 3 (publish next buffers)
            __builtin_amdgcn_sched_barrier(0);
        }
        __builtin_amdgcn_s_setprio(1);
        #pragma unroll
        for (int mt = 0; mt < 4; ++mt)
            #pragma unroll
            for (int nt = 0; nt < 4; ++nt)
                acc[mt + 4][nt] = __builtin_amdgcn_mfma_f32_16x16x32_bf16(afr1[mt], bfr[nt], acc[mt + 4][nt], 0, 0, 0);
        __builtin_amdgcn_s_setprio(0);
    }

    // ---- epilogue: store M[bz][iloc][j] bf16 ----
    #pragma unroll
    for (int mt = 0; mt < 8; ++mt)
        #pragma unroll
        for (int nt = 0; nt < 4; ++nt)
            #pragma unroll
            for (int r = 0; r < 4; ++r) {
                int bz = bzg * 128 + mt * 16 + l4 * 4 + r;
                int j  = j0 + jg * 64 + nt * 16 + l15;
                Mws[(size_t)bz * 262144 + (size_t)iloc * 512 + j] = f2bf(acc[mt][nt][r]);
            }
}

// ---------------- G2 v4 (round-7 best): Y staged once; M depth-4; X depth-3 ----------------
__global__ __launch_bounds__(512, 2) void k_fuse(const unsigned short* __restrict__ xbf,
    const unsigned short* __restrict__ ybf, const unsigned short* __restrict__ Mws,
    const float* __restrict__ xf, const float* __restrict__ yf,
    const float* __restrict__ a_arr, const float* __restrict__ c_arr,
    const float* __restrict__ d_arr, float* __restrict__ out)
{
    extern __shared__ unsigned char smem[];    // 131072: Y, later reused as R
    __shared__ float part[512];
    __shared__ float uv[256];

    int bid = blockIdx.x;
    int bz = (bid & 7) * 64 + (bid >> 3);      // XCD swizzle (512 = 8*64)
    int b = bz >> 7;
    int t = threadIdx.x, wid = t >> 6, lane = t & 63;
    int l15 = lane & 15, l4 = lane >> 4;
    int xg = wid >> 2, yg = wid & 3;
    int g8 = wid;

    // ---- stage Y once: LDS[row][slot] = Y[row][slot ^ (row&63)] ----
    const unsigned short* ybase = ybf + (size_t)(b * 128) * 512;
    #pragma unroll
    for (int it = 0; it < 16; ++it) {
        int row = it * 8 + wid;
        gload_lds16(ybase + (size_t)row * 512 + ((lane ^ (row & 63)) * 8),
                    smem + it * 8192 + t * 16);
    }

    // ---- bias u/v (LDS scratch; syncthreads drain Y staging too) ----
    {
        int xr = t & 127, q = t >> 7;
        {   const float* xp = xf + (size_t)(b * 128 + xr) * 512 + q * 128;
            const float* ap = a_arr + bz * 512 + q * 128;
            float s = 0.f;
            for (int ii = 0; ii < 128; ++ii) s += xp[ii] * ap[ii];
            part[q * 128 + xr] = s;
        }
        __syncthreads();
        if (t < 128) uv[t] = part[t] + part[128 + t] + part[256 + t] + part[384 + t];
        __syncthreads();
        {   const float* yp = yf + (size_t)(b * 128 + xr) * 512 + q * 128;
            const float* cp = c_arr + bz * 512 + q * 128;
            float s = 0.f;
            for (int ii = 0; ii < 128; ++ii) s += yp[ii] * cp[ii];
            part[q * 128 + xr] = s;
        }
        __syncthreads();
        if (t < 128) uv[128 + t] = part[t] + part[128 + t] + part[256 + t] + part[384 + t];
        __syncthreads();
    }

    // ---- pass-2: accR = M x Y^T over all 512 j (M depth-4 prefetch) ----
    const unsigned short* mbase = Mws + (size_t)bz * 262144
                                + (size_t)(g8 * 64 + l15) * 512 + l4 * 8;
    f32x4 accR[4][8];
    #pragma unroll
    for (int mt = 0; mt < 4; ++mt)
        #pragma unroll
        for (int nt = 0; nt < 8; ++nt) accR[mt][nt] = (f32x4){0.f, 0.f, 0.f, 0.f};

    bf16x8 mfr[4][4];
    #pragma unroll
    for (int d = 0; d < 4; ++d)
        #pragma unroll
        for (int mt = 0; mt < 4; ++mt)
            mfr[d][mt] = *(const bf16x8*)(mbase + (size_t)mt * 8192 + d * 32);

    #pragma unroll
    for (int kf = 0; kf < 16; ++kf) {
        #pragma unroll
        for (int nh = 0; nh < 2; ++nh) {       // y-frags in halves of 4 (VGPR cap)
            bf16x8 yfr[4];
            #pragma unroll
            for (int n4 = 0; n4 < 4; ++n4) {
                int y = (nh * 4 + n4) * 16 + l15;
                yfr[n4] = *(const bf16x8*)(smem + y * 1024 + (((kf * 4 + l4) ^ (y & 63)) * 16));
            }
            #pragma unroll
            for (int mt = 0; mt < 4; ++mt)
                #pragma unroll
                for (int n4 = 0; n4 < 4; ++n4)
                    accR[mt][nh * 4 + n4] = __builtin_amdgcn_mfma_f32_16x16x32_bf16(
                        mfr[kf & 3][mt], yfr[n4], accR[mt][nh * 4 + n4], 0, 0, 0);
        }
        if (kf < 12) {
            #pragma unroll
            for (int mt = 0; mt < 4; ++mt)
                mfr[kf & 3][mt] = *(const bf16x8*)(mbase + (size_t)mt * 8192 + (kf + 4) * 32);
        }
    }
    asm volatile("s_waitcnt lgkmcnt(0)" ::: "memory");
    __builtin_amdgcn_s_barrier();
    __builtin_amdgcn_sched_barrier(0);

    // ---- write R[y][i] bf16 over Y region (same swizzle: slot = chunk^(y&63)) ----
    #pragma unroll
    for (int mt = 0; mt < 4; ++mt)
        #pragma unroll
        for (int nt = 0; nt < 8; ++nt) {
            int y = nt * 16 + l15;
            int chunk = g8 * 8 + mt * 2 + (l4 >> 1);
            int byte = y * 1024 + ((chunk ^ (y & 63)) * 16) + (l4 & 1) * 8;
            unsigned p0 = f2bf(accR[mt][nt][0]) | ((unsigned)f2bf(accR[mt][nt][1]) << 16);
            unsigned p1 = f2bf(accR[mt][nt][2]) | ((unsigned)f2bf(accR[mt][nt][3]) << 16);
            *(uint2*)(smem + byte) = make_uint2(p0, p1);
        }
    asm volatile("s_waitcnt lgkmcnt(0)" ::: "memory");
    __builtin_amdgcn_s_barrier();
    __builtin_amdgcn_sched_barrier(0);

    // ---- acc init from bias (deferred; uv persists in static LDS) ----
    float dv = d_arr[bz];
    f32x4 acc[4][2];
    #pragma unroll
    for (int mt = 0; mt < 4; ++mt)
        #pragma unroll
        for (int nt = 0; nt < 2; ++nt) {
            int y = yg * 32 + nt * 16 + l15;
            #pragma unroll
            for (int r = 0; r < 4; ++r) {
                int x = xg * 64 + mt * 16 + l4 * 4 + r;
                acc[mt][nt][r] = uv[x] + uv[128 + y] + dv;
            }
        }

    // ---- pass-3: acc += X x R over all 512 i (X depth-3) ----
    const unsigned short* xbase = xbf + (size_t)(b * 128 + xg * 64 + l15) * 512 + l4 * 8;
    bf16x8 xfr[3][4];
    #pragma unroll
    for (int d = 0; d < 3; ++d)
        #pragma unroll
        for (int mt = 0; mt < 4; ++mt)
            xfr[d][mt] = *(const bf16x8*)(xbase + (size_t)mt * 8192 + d * 32);

    #pragma unroll
    for (int kf = 0; kf < 16; ++kf) {
        bf16x8 rfr[2];
        #pragma unroll
        for (int nt = 0; nt < 2; ++nt) {
            int y = yg * 32 + nt * 16 + l15;
            rfr[nt] = *(const bf16x8*)(smem + y * 1024 + (((kf * 4 + l4) ^ (y & 63)) * 16));
        }
        #pragma unroll
        for (int mt = 0; mt < 4; ++mt)
            #pragma unroll
            for (int nt = 0; nt < 2; ++nt)
                acc[mt][nt] = __builtin_amdgcn_mfma_f32_16x16x32_bf16(
                    xfr[kf % 3][mt], rfr[nt], acc[mt][nt], 0, 0, 0);
        if (kf < 13) {
            #pragma unroll
            for (int mt = 0; mt < 4; ++mt)
                xfr[kf % 3][mt] = *(const bf16x8*)(xbase + (size_t)mt * 8192 + (kf + 3) * 32);
        }
    }

    // ---- epilogue ----
    float* op = out + (size_t)bz * 16384;
    #pragma unroll
    for (int mt = 0; mt < 4; ++mt)
        #pragma unroll
        for (int nt = 0; nt < 2; ++nt)
            #pragma unroll
            for (int r = 0; r < 4; ++r) {
                int x = xg * 64 + mt * 16 + l4 * 4 + r;
                int y = yg * 32 + nt * 16 + l15;
                op[x * 128 + y] = acc[mt][nt][r];
            }
}

extern "C" void kernel_launch(void* const* d_in, const int* in_sizes, int n_in,
                              void* d_out, int out_size, void* d_ws, size_t ws_size,
                              hipStream_t stream)
{
    const float* x = (const float*)d_in[0];
    const float* y = (const float*)d_in[1];
    const float* z = (const float*)d_in[2];
    const float* w = (const float*)d_in[3];
    float* out = (float*)d_out;
    char* ws = (char*)d_ws;

    unsigned short* xbf = (unsigned short*)(ws + 0);
    unsigned short* ybf = (unsigned short*)(ws + 524288);
    unsigned short* zbf = (unsigned short*)(ws + 1048576);
    float* a_arr = (float*)(ws + 1572864);
    float* c_arr = (float*)(ws + 2621440);
    float* d_arr = (float*)(ws + 3670016);
    unsigned short* Mws = (unsigned short*)(ws + 3674112);   // 512*512*512 bf16 = 268 MB

    hipLaunchKernelGGL(k_cast, dim3(384), dim3(256), 0, stream, x, y, z, xbf, ybf, zbf);
    hipLaunchKernelGGL(k_edge, dim3(136), dim3(256), 0, stream, z, w, a_arr, c_arr, d_arr);
    hipLaunchKernelGGL(k_gemm1, dim3(2048), dim3(512), 81920, stream, zbf, w, Mws);
    hipLaunchKernelGGL(k_fuse, dim3(512), dim3(512), 131072, stream, xbf, ybf, Mws,
                       x, y, a_arr, c_arr, d_arr, out);
}

// Round 10
// 445.467 us; speedup vs baseline: 1.1028x; 1.1028x over previous
//
#include <hip/hip_runtime.h>
#include <stdint.h>

// Triaffine: out[b,z,x,y] = sum_{i,j,k} xb[x,i] z[z,k] W[i,k,j] yb[y,j]
// B=4, S=128, D=512.  W: [513][512][513] f32 (i,k,j), elem (i,k,j) at (i*512+k)*513+j.
//
// Decomposition (bias split so all GEMM dims are 512):
//   M[bz,i,j] = sum_k z[bz,k] W[i,k,j]        (i,j < 512)   -- k_gemm1, bf16 out
//   per bz:  R[i,y] = sum_j M[i,j] Ybf[y,j]                  -- k_fuse pass-2
//            out[x,y] = sum_i Xbf[x,i] R[i,y] + u[x]+v[y]+d  -- k_fuse pass-3
//   a[bz,i], c[bz,j], d[bz] from W edges (k_edge); u=x.a, v=y.c (k_uv)

typedef __attribute__((ext_vector_type(8))) short bf16x8;
typedef __attribute__((ext_vector_type(4))) float f32x4;

__device__ __forceinline__ unsigned short f2bf(float f) {
    unsigned int u = __float_as_uint(f);
    u += 0x7fffu + ((u >> 16) & 1u);      // RNE
    return (unsigned short)(u >> 16);
}

__device__ __forceinline__ void gload_lds16(const void* g, void* l) {
    __builtin_amdgcn_global_load_lds((const __attribute__((address_space(1))) void*)g,
                                     (__attribute__((address_space(3))) void*)l, 16, 0, 0);
}

// ---------------- cast x,y,z -> bf16 ----------------
__global__ __launch_bounds__(256) void k_cast(const float* __restrict__ x,
    const float* __restrict__ y, const float* __restrict__ z,
    unsigned short* __restrict__ xbf, unsigned short* __restrict__ ybf,
    unsigned short* __restrict__ zbf)
{
    int t = blockIdx.x * 256 + threadIdx.x;   // 98304 threads, 8 elems each
    int arr = t >> 15;
    int off = (t & 32767) * 8;
    const float* src = (arr == 0) ? x : (arr == 1) ? y : z;
    unsigned short* dst = (arr == 0) ? xbf : (arr == 1) ? ybf : zbf;
    float4 a = *(const float4*)(src + off);
    float4 b = *(const float4*)(src + off + 4);
    uint4 o;
    o.x = f2bf(a.x) | ((unsigned)f2bf(a.y) << 16);
    o.y = f2bf(a.z) | ((unsigned)f2bf(a.w) << 16);
    o.z = f2bf(b.x) | ((unsigned)f2bf(b.y) << 16);
    o.w = f2bf(b.z) | ((unsigned)f2bf(b.w) << 16);
    *(uint4*)(dst + off) = o;
}

// ---------------- bias-edge GEMMs ----------------
__global__ __launch_bounds__(256) void k_edge(const float* __restrict__ z,
    const float* __restrict__ w, float* __restrict__ a_arr,
    float* __restrict__ c_arr, float* __restrict__ d_arr)
{
    __shared__ float Zs[64][33];
    __shared__ float Bs[32][65];
    int t = threadIdx.x;
    int mb = blockIdx.x % 17, bzb = blockIdx.x / 17;
    int tr = t >> 4, tc = t & 15;
    float acc[4][4] = {};
    for (int k0 = 0; k0 < 512; k0 += 32) {
        __syncthreads();
        {   int row = t >> 2, ko = (t & 3) * 8;
            const float* p = z + (bzb * 64 + row) * 512 + k0 + ko;
            float4 v0 = ((const float4*)p)[0], v1 = ((const float4*)p)[1];
            Zs[row][ko + 0] = v0.x; Zs[row][ko + 1] = v0.y; Zs[row][ko + 2] = v0.z; Zs[row][ko + 3] = v0.w;
            Zs[row][ko + 4] = v1.x; Zs[row][ko + 5] = v1.y; Zs[row][ko + 6] = v1.z; Zs[row][ko + 7] = v1.w;
        }
        {   int kr = t >> 3, mo = (t & 7) * 8;
            for (int e = 0; e < 8; ++e) {
                int m = mb * 64 + mo + e;
                float v = 0.f;
                int krow = k0 + kr;
                if (m < 512)        v = w[(m * 512 + krow) * 513 + 512];
                else if (m < 1024)  v = w[(262144 + krow) * 513 + (m - 512)];
                else if (m == 1024) v = w[(262144 + krow) * 513 + 512];
                Bs[kr][mo + e] = v;
            }
        }
        __syncthreads();
        for (int kk = 0; kk < 32; ++kk) {
            float zr[4], br[4];
            for (int r = 0; r < 4; ++r) zr[r] = Zs[tr * 4 + r][kk];
            for (int c = 0; c < 4; ++c) br[c] = Bs[kk][tc * 4 + c];
            for (int r = 0; r < 4; ++r)
                for (int c = 0; c < 4; ++c) acc[r][c] += zr[r] * br[c];
        }
    }
    for (int r = 0; r < 4; ++r)
        for (int c = 0; c < 4; ++c) {
            int bz = bzb * 64 + tr * 4 + r;
            int m = mb * 64 + tc * 4 + c;
            if (m < 512)        a_arr[bz * 512 + m] = acc[r][c];
            else if (m < 1024)  c_arr[bz * 512 + (m - 512)] = acc[r][c];
            else if (m == 1024) d_arr[bz] = acc[r][c];
        }
}

// ---------------- k_uv: u[bz,x] = x.a_bz, v[bz,y] = y.c_bz (coalesced) ----------------
__global__ __launch_bounds__(512) void k_uv(const float* __restrict__ xf,
    const float* __restrict__ yf, const float* __restrict__ a_arr,
    const float* __restrict__ c_arr, float* __restrict__ u_arr,
    float* __restrict__ v_arr)
{
    __shared__ float part[512];
    int bz = blockIdx.x;
    int b = bz >> 7;
    int t = threadIdx.x, r = t >> 2, q = t & 3;
    {
        const float* xp = xf + (size_t)(b * 128 + r) * 512;
        const float* ap = a_arr + bz * 512;
        float s = 0.f;
        #pragma unroll 4
        for (int c0 = 0; c0 < 32; ++c0) {
            int col = c0 * 16 + q * 4;
            float4 xv = *(const float4*)(xp + col);
            float4 av = *(const float4*)(ap + col);
            s += xv.x * av.x + xv.y * av.y + xv.z * av.z + xv.w * av.w;
        }
        part[t] = s;
    }
    __syncthreads();
    if (t < 128) u_arr[bz * 128 + t] = part[t*4] + part[t*4+1] + part[t*4+2] + part[t*4+3];
    __syncthreads();
    {
        const float* yp = yf + (size_t)(b * 128 + r) * 512;
        const float* cp = c_arr + bz * 512;
        float s = 0.f;
        #pragma unroll 4
        for (int c0 = 0; c0 < 32; ++c0) {
            int col = c0 * 16 + q * 4;
            float4 yv = *(const float4*)(yp + col);
            float4 cv = *(const float4*)(cp + col);
            s += yv.x * cv.x + yv.y * cv.y + yv.z * cv.z + yv.w * cv.w;
        }
        part[t] = s;
    }
    __syncthreads();
    if (t < 128) v_arr[bz * 128 + t] = part[t*4] + part[t*4+1] + part[t*4+2] + part[t*4+3];
}

// ---------------- G1 (round-7 best, unchanged) ----------------
__global__ __launch_bounds__(512, 2) void k_gemm1(const unsigned short* __restrict__ zbf,
    const float* __restrict__ w, unsigned short* __restrict__ Mws)
{
    extern __shared__ unsigned char smem[];
    unsigned char* Zb0 = smem;                 // [512 rows][32 k] bf16 = 32 KB
    unsigned char* Zb1 = smem + 32768;
    unsigned char* Bb0 = smem + 65536;         // [128 j][32 k] bf16 = 8 KB
    unsigned char* Bb1 = smem + 73728;         // total 81920 B

    int nwg = gridDim.x, cpx = nwg >> 3;
    int bid = blockIdx.x;
    int swz = (bid & 7) * cpx + (bid >> 3);    // XCD swizzle (nwg % 8 == 0)
    int iloc = swz >> 2, jb = swz & 3;
    int j0 = jb * 128;
    int t = threadIdx.x, wid = t >> 6, lane = t & 63;
    int bzg = wid >> 1, jg = wid & 1;
    int l15 = lane & 15, l4 = lane >> 4;

    int arow = lane >> 2;
    int akc  = (lane & 3) ^ ((lane >> 3) & 3);
    const unsigned short* zbase = zbf + (size_t)(wid * 64 + arow) * 512 + akc * 8;

    int jB = t & 127, kq8 = t >> 7;
    const float* wb = w + (size_t)iloc * 262656 + (size_t)(kq8 * 8) * 513 + j0 + jB;
    int bwoff = jB * 64 + ((kq8 ^ ((jB >> 1) & 3)) * 16);

    int aoff = (bzg * 128 + l15) * 64 + ((l4 ^ ((l15 >> 1) & 3)) * 16);
    int boff = (jg * 64 + l15) * 64 + ((l4 ^ ((l15 >> 1) & 3)) * 16);

    f32x4 acc[8][4];
    #pragma unroll
    for (int mt = 0; mt < 8; ++mt)
        #pragma unroll
        for (int nt = 0; nt < 4; ++nt) acc[mt][nt] = (f32x4){0.f, 0.f, 0.f, 0.f};

    float wr[2][8];

    #pragma unroll
    for (int q = 0; q < 4; ++q)
        gload_lds16(zbase + q * 8192, Zb0 + wid * 4096 + q * 1024);
    {
        #pragma unroll
        for (int e = 0; e < 8; ++e) wr[0][e] = __builtin_nontemporal_load(wb + (size_t)e * 513);
        const float* wp = wb + (size_t)32 * 513;
        #pragma unroll
        for (int e = 0; e < 8; ++e) wr[1][e] = __builtin_nontemporal_load(wp + (size_t)e * 513);
        uint4 pk;
        pk.x = f2bf(wr[0][0]) | ((unsigned)f2bf(wr[0][1]) << 16);
        pk.y = f2bf(wr[0][2]) | ((unsigned)f2bf(wr[0][3]) << 16);
        pk.z = f2bf(wr[0][4]) | ((unsigned)f2bf(wr[0][5]) << 16);
        pk.w = f2bf(wr[0][6]) | ((unsigned)f2bf(wr[0][7]) << 16);
        *(uint4*)(Bb0 + bwoff) = pk;
    }
    asm volatile("s_waitcnt lgkmcnt(0)" ::: "memory");
    __builtin_amdgcn_s_barrier();
    __builtin_amdgcn_sched_barrier(0);

    #pragma unroll
    for (int ks = 0; ks < 16; ++ks) {
        const int cur = ks & 1;
        unsigned char* Zcur  = cur ? Zb1 : Zb0;
        unsigned char* Znext = cur ? Zb0 : Zb1;
        unsigned char* Bcur  = cur ? Bb1 : Bb0;
        unsigned char* Bnext = cur ? Bb0 : Bb1;

        if (ks < 15) {
            #pragma unroll
            for (int q = 0; q < 4; ++q)
                gload_lds16(zbase + (ks + 1) * 32 + q * 8192, Znext + wid * 4096 + q * 1024);
        }
        if (ks < 14) {
            const float* wp = wb + (size_t)(ks + 2) * 32 * 513;
            #pragma unroll
            for (int e = 0; e < 8; ++e) wr[cur][e] = __builtin_nontemporal_load(wp + (size_t)e * 513);
        }
        bf16x8 bfr[4];
        #pragma unroll
        for (int nt = 0; nt < 4; ++nt)
            bfr[nt] = *(const bf16x8*)(Bcur + boff + nt * 1024);
        #pragma unroll
        for (int mt = 0; mt < 8; ++mt) {
            bf16x8 afr = *(const bf16x8*)(Zcur + aoff + mt * 1024);
            #pragma unroll
            for (int nt = 0; nt < 4; ++nt)
                acc[mt][nt] = __builtin_amdgcn_mfma_f32_16x16x32_bf16(afr, bfr[nt], acc[mt][nt], 0, 0, 0);
        }
        if (ks < 15) {
            uint4 pk;
            pk.x = f2bf(wr[cur ^ 1][0]) | ((unsigned)f2bf(wr[cur ^ 1][1]) << 16);
            pk.y = f2bf(wr[cur ^ 1][2]) | ((unsigned)f2bf(wr[cur ^ 1][3]) << 16);
            pk.z = f2bf(wr[cur ^ 1][4]) | ((unsigned)f2bf(wr[cur ^ 1][5]) << 16);
            pk.w = f2bf(wr[cur ^ 1][6]) | ((unsigned)f2bf(wr[cur ^ 1][7]) << 16);
            *(uint4*)(Bnext + bwoff) = pk;
        }
        if (ks < 14) {
            asm volatile("s_waitcnt vmcnt(8) lgkmcnt(0)" ::: "memory");
        } else if (ks == 14) {
            asm volatile("s_waitcnt vmcnt(0) lgkmcnt(0)" ::: "memory");
        }
        if (ks < 15) {
            __builtin_amdgcn_s_barrier();
            __builtin_amdgcn_sched_barrier(0);
        }
    }

    #pragma unroll
    for (int mt = 0; mt < 8; ++mt)
        #pragma unroll
        for (int nt = 0; nt < 4; ++nt)
            #pragma unroll
            for (int r = 0; r < 4; ++r) {
                int bz = bzg * 128 + mt * 16 + l4 * 4 + r;
                int j  = j0 + jg * 64 + nt * 16 + l15;
                Mws[(size_t)bz * 262144 + (size_t)iloc * 512 + j] = f2bf(acc[mt][nt][r]);
            }
}

// ---------------- G2 v5: bias offloaded; Y/M and R-write/X overlapped ----------------
// 8 waves, 1 WG/CU. Y[128 y][512 j] in LDS (128 KB, slot = chunk^(row&63));
// pass-2 K=512 with M direct global depth-4 (first 16 M loads issued UNDER the
// Y-stage barrier via vmcnt(16)); R overwrites Y; pass-3 X direct global with
// its 12 frag loads issued BEFORE the R-write barriers; u/v/d folded in epilogue.
__global__ __launch_bounds__(512, 2) void k_fuse(const unsigned short* __restrict__ xbf,
    const unsigned short* __restrict__ ybf, const unsigned short* __restrict__ Mws,
    const float* __restrict__ u_arr, const float* __restrict__ v_arr,
    const float* __restrict__ d_arr, float* __restrict__ out)
{
    extern __shared__ unsigned char smem[];    // 131072: Y, later reused as R

    int bid = blockIdx.x;
    int bz = (bid & 7) * 64 + (bid >> 3);      // XCD swizzle (512 = 8*64)
    int b = bz >> 7;
    int t = threadIdx.x, wid = t >> 6, lane = t & 63;
    int l15 = lane & 15, l4 = lane >> 4;
    int xg = wid >> 2, yg = wid & 3;
    int g8 = wid;

    // ---- issue Y staging (16 gload_lds / thread) ----
    const unsigned short* ybase = ybf + (size_t)(b * 128) * 512;
    #pragma unroll
    for (int it = 0; it < 16; ++it) {
        int row = it * 8 + wid;
        gload_lds16(ybase + (size_t)row * 512 + ((lane ^ (row & 63)) * 8),
                    smem + it * 8192 + t * 16);
    }

    // ---- issue first M prefetch (depth-4, 16 loads) BEFORE the Y barrier ----
    const unsigned short* mbase = Mws + (size_t)bz * 262144
                                + (size_t)(g8 * 64 + l15) * 512 + l4 * 8;
    bf16x8 mfr[4][4];
    #pragma unroll
    for (int d = 0; d < 4; ++d)
        #pragma unroll
        for (int mt = 0; mt < 4; ++mt)
            mfr[d][mt] = *(const bf16x8*)(mbase + (size_t)mt * 8192 + d * 32);

    // drain only Y's gload_lds (16 M loads remain in flight), publish Y
    asm volatile("s_waitcnt vmcnt(16)" ::: "memory");
    __builtin_amdgcn_s_barrier();
    __builtin_amdgcn_sched_barrier(0);

    // ---- pass-2: accR = M x Y^T over all 512 j ----
    f32x4 accR[4][8];
    #pragma unroll
    for (int mt = 0; mt < 4; ++mt)
        #pragma unroll
        for (int nt = 0; nt < 8; ++nt) accR[mt][nt] = (f32x4){0.f, 0.f, 0.f, 0.f};

    #pragma unroll
    for (int kf = 0; kf < 16; ++kf) {
        #pragma unroll
        for (int nh = 0; nh < 2; ++nh) {       // y-frags in halves of 4 (VGPR cap)
            bf16x8 yfr[4];
            #pragma unroll
            for (int n4 = 0; n4 < 4; ++n4) {
                int y = (nh * 4 + n4) * 16 + l15;
                yfr[n4] = *(const bf16x8*)(smem + y * 1024 + (((kf * 4 + l4) ^ (y & 63)) * 16));
            }
            #pragma unroll
            for (int mt = 0; mt < 4; ++mt)
                #pragma unroll
                for (int n4 = 0; n4 < 4; ++n4)
                    accR[mt][nh * 4 + n4] = __builtin_amdgcn_mfma_f32_16x16x32_bf16(
                        mfr[kf & 3][mt], yfr[n4], accR[mt][nh * 4 + n4], 0, 0, 0);
        }
        if (kf < 12) {
            #pragma unroll
            for (int mt = 0; mt < 4; ++mt)
                mfr[kf & 3][mt] = *(const bf16x8*)(mbase + (size_t)mt * 8192 + (kf + 4) * 32);
        }
    }

    // ---- issue pass-3 X fragment loads (12) before the R-write barriers ----
    const unsigned short* xbase = xbf + (size_t)(b * 128 + xg * 64 + l15) * 512 + l4 * 8;
    bf16x8 xfr[3][4];
    #pragma unroll
    for (int d = 0; d < 3; ++d)
        #pragma unroll
        for (int mt = 0; mt < 4; ++mt)
            xfr[d][mt] = *(const bf16x8*)(xbase + (size_t)mt * 8192 + d * 32);

    asm volatile("s_waitcnt lgkmcnt(0)" ::: "memory");
    __builtin_amdgcn_s_barrier();              // all waves done reading Y
    __builtin_amdgcn_sched_barrier(0);

    // ---- write R[y][i] bf16 over Y region (same swizzle: slot = chunk^(y&63)) ----
    #pragma unroll
    for (int mt = 0; mt < 4; ++mt)
        #pragma unroll
        for (int nt = 0; nt < 8; ++nt) {
            int y = nt * 16 + l15;
            int chunk = g8 * 8 + mt * 2 + (l4 >> 1);
            int byte = y * 1024 + ((chunk ^ (y & 63)) * 16) + (l4 & 1) * 8;
            unsigned p0 = f2bf(accR[mt][nt][0]) | ((unsigned)f2bf(accR[mt][nt][1]) << 16);
            unsigned p1 = f2bf(accR[mt][nt][2]) | ((unsigned)f2bf(accR[mt][nt][3]) << 16);
            *(uint2*)(smem + byte) = make_uint2(p0, p1);
        }
    asm volatile("s_waitcnt lgkmcnt(0)" ::: "memory");
    __builtin_amdgcn_s_barrier();              // R visible (X loads still in flight)
    __builtin_amdgcn_sched_barrier(0);

    // ---- pass-3: acc = X x R over all 512 i ----
    f32x4 acc[4][2];
    #pragma unroll
    for (int mt = 0; mt < 4; ++mt)
        #pragma unroll
        for (int nt = 0; nt < 2; ++nt) acc[mt][nt] = (f32x4){0.f, 0.f, 0.f, 0.f};

    #pragma unroll
    for (int kf = 0; kf < 16; ++kf) {
        bf16x8 rfr[2];
        #pragma unroll
        for (int nt = 0; nt < 2; ++nt) {
            int y = yg * 32 + nt * 16 + l15;
            rfr[nt] = *(const bf16x8*)(smem + y * 1024 + (((kf * 4 + l4) ^ (y & 63)) * 16));
        }
        #pragma unroll
        for (int mt = 0; mt < 4; ++mt)
            #pragma unroll
            for (int nt = 0; nt < 2; ++nt)
                acc[mt][nt] = __builtin_amdgcn_mfma_f32_16x16x32_bf16(
                    xfr[kf % 3][mt], rfr[nt], acc[mt][nt], 0, 0, 0);
        if (kf < 13) {
            #pragma unroll
            for (int mt = 0; mt < 4; ++mt)
                xfr[kf % 3][mt] = *(const bf16x8*)(xbase + (size_t)mt * 8192 + (kf + 3) * 32);
        }
    }

    // ---- epilogue: out = acc + u[x] + v[y] + d ----
    float dv = d_arr[bz];
    float* op = out + (size_t)bz * 16384;
    #pragma unroll
    for (int mt = 0; mt < 4; ++mt) {
        float4 uq = *(const float4*)(u_arr + bz * 128 + xg * 64 + mt * 16 + l4 * 4);
        #pragma unroll
        for (int nt = 0; nt < 2; ++nt) {
            int y = yg * 32 + nt * 16 + l15;
            float vv = v_arr[bz * 128 + y] + dv;
            int x0 = xg * 64 + mt * 16 + l4 * 4;
            op[(x0 + 0) * 128 + y] = acc[mt][nt][0] + uq.x + vv;
            op[(x0 + 1) * 128 + y] = acc[mt][nt][1] + uq.y + vv;
            op[(x0 + 2) * 128 + y] = acc[mt][nt][2] + uq.z + vv;
            op[(x0 + 3) * 128 + y] = acc[mt][nt][3] + uq.w + vv;
        }
    }
}

extern "C" void kernel_launch(void* const* d_in, const int* in_sizes, int n_in,
                              void* d_out, int out_size, void* d_ws, size_t ws_size,
                              hipStream_t stream)
{
    const float* x = (const float*)d_in[0];
    const float* y = (const float*)d_in[1];
    const float* z = (const float*)d_in[2];
    const float* w = (const float*)d_in[3];
    float* out = (float*)d_out;
    char* ws = (char*)d_ws;

    unsigned short* xbf = (unsigned short*)(ws + 0);           // 512 KB
    unsigned short* ybf = (unsigned short*)(ws + 524288);      // 512 KB
    unsigned short* zbf = (unsigned short*)(ws + 1048576);     // 512 KB
    float* a_arr = (float*)(ws + 1572864);                     // 1 MB
    float* c_arr = (float*)(ws + 2621440);                     // 1 MB
    float* d_arr = (float*)(ws + 3670016);                     // 2 KB
    float* u_arr = (float*)(ws + 3674112);                     // 256 KB
    float* v_arr = (float*)(ws + 3936256);                     // 256 KB
    unsigned short* Mws = (unsigned short*)(ws + 4198400);     // 268 MB

    hipLaunchKernelGGL(k_cast, dim3(384), dim3(256), 0, stream, x, y, z, xbf, ybf, zbf);
    hipLaunchKernelGGL(k_edge, dim3(136), dim3(256), 0, stream, z, w, a_arr, c_arr, d_arr);
    hipLaunchKernelGGL(k_uv, dim3(512), dim3(512), 0, stream, x, y, a_arr, c_arr, u_arr, v_arr);
    hipLaunchKernelGGL(k_gemm1, dim3(2048), dim3(512), 81920, stream, zbf, w, Mws);
    hipLaunchKernelGGL(k_fuse, dim3(512), dim3(512), 131072, stream, xbf, ybf, Mws,
                       u_arr, v_arr, d_arr, out);
}